// Round 2
// baseline (76.572 us; speedup 1.0000x reference)
//
#include <hip/hip_runtime.h>

#define FDIM 1024
#define BDIM 512
#define PDIM 512

__device__ __forceinline__ unsigned sad8(unsigned a, unsigned b, unsigned c) {
  return __builtin_amdgcn_sad_u8(a, b, c);  // sum_{4 bytes} |a_i - b_i| + c
}

// One block per row (rows 0..511 = x, 512..1023 = w).
// Sigmoid -> u8 quantize (scale 255) -> packed dword store. No reductions.
__global__ __launch_bounds__(256) void quant_kernel(
    const float* __restrict__ x, const float* __restrict__ w,
    unsigned* __restrict__ xq, unsigned* __restrict__ wq) {
  const int row = blockIdx.x;   // 0..1023
  const int tid = threadIdx.x;  // 0..255, each handles 4 floats
  const bool isx = row < BDIM;
  const float* src = isx ? (x + (size_t)row * FDIM)
                         : (w + (size_t)(row - BDIM) * FDIM);
  float4 v = ((const float4*)src)[tid];
  float s0 = 1.f / (1.f + __expf(-v.x));
  float s1 = 1.f / (1.f + __expf(-v.y));
  float s2 = 1.f / (1.f + __expf(-v.z));
  float s3 = 1.f / (1.f + __expf(-v.w));
  unsigned q0 = (unsigned)(s0 * 255.f + 0.5f);
  unsigned q1 = (unsigned)(s1 * 255.f + 0.5f);
  unsigned q2 = (unsigned)(s2 * 255.f + 0.5f);
  unsigned q3 = (unsigned)(s3 * 255.f + 0.5f);
  unsigned* dq = isx ? (xq + row * (FDIM / 4)) : (wq + (row - BDIM) * (FDIM / 4));
  dq[tid] = q0 | (q1 << 8) | (q2 << 16) | (q3 << 24);
}

// Block: 64 b-rows (lane) x 8 p-cols; 4 waves each own a 256-byte F-slice.
// D[b,p] = sum_f |xq - wq| via v_sad_u8. Row sums Sx/Sw computed in-block
// (sad8 against 0 = byte sum), so no extra workspace needed.
__global__ __launch_bounds__(256) void tversky_pair(
    const unsigned* __restrict__ xq, const unsigned* __restrict__ wq,
    const float* __restrict__ bias, const float* __restrict__ alphap,
    const float* __restrict__ betap, float* __restrict__ out) {
  const int tid = threadIdx.x;
  const int lane = tid & 63;
  const int wv = tid >> 6;              // F-slice id 0..3
  const int r = blockIdx.y * 64 + lane; // b row, 0..511
  const int c0 = blockIdx.x * 8;        // p col base, 0..504

  __shared__ unsigned part[4][8][64];   // D partials [slice][p][b]
  __shared__ unsigned sxp[4][64];       // Sx partials [slice][b]
  __shared__ unsigned swsum[8];         // Sw per p col

  if (tid < 8) swsum[tid] = 0;
  __syncthreads();

  // Load this lane's 256-byte x slice (64 dwords) into registers.
  const uint4* x4 = (const uint4*)(xq + r * (FDIM / 4) + wv * 64);
  uint4 xv[16];
#pragma unroll
  for (int j = 0; j < 16; ++j) xv[j] = x4[j];

  // Sx slice sum: sad against 0 = byte sum.
  unsigned sx = 0;
#pragma unroll
  for (int j = 0; j < 16; ++j) {
    sx = sad8(xv[j].x, 0u, sx);
    sx = sad8(xv[j].y, 0u, sx);
    sx = sad8(xv[j].z, 0u, sx);
    sx = sad8(xv[j].w, 0u, sx);
  }
  sxp[wv][lane] = sx;

  // Sw for the 8 w rows of this block: thread t sums 8 dwords of row t>>5.
  {
    const int wrow = tid >> 5;  // 0..7
    const int seg = tid & 31;   // 0..31
    const unsigned* wp = wq + (c0 + wrow) * (FDIM / 4) + seg * 8;
    unsigned s = 0;
#pragma unroll
    for (int j = 0; j < 8; ++j) s = sad8(wp[j], 0u, s);
    atomicAdd(&swsum[wrow], s);
  }

  // Main pairwise loop: 8 cols x 64 sads, 4 independent chains.
  for (int pp = 0; pp < 8; ++pp) {
    const uint4* w4 = (const uint4*)(wq + (c0 + pp) * (FDIM / 4) + wv * 64);
    unsigned a0 = 0, a1 = 0, a2 = 0, a3 = 0;
#pragma unroll
    for (int j = 0; j < 16; ++j) {
      uint4 ww = w4[j];
      a0 = sad8(xv[j].x, ww.x, a0);
      a1 = sad8(xv[j].y, ww.y, a1);
      a2 = sad8(xv[j].z, ww.z, a2);
      a3 = sad8(xv[j].w, ww.w, a3);
    }
    part[wv][pp][lane] = a0 + a1 + a2 + a3;
  }
  __syncthreads();

  const float alpha = alphap[0];
  const float beta = betap[0];
#pragma unroll
  for (int id = tid; id < 512; id += 256) {
    const int row = id >> 3;
    const int pp = id & 7;
    const unsigned D = part[0][pp][row] + part[1][pp][row] +
                       part[2][pp][row] + part[3][pp][row];
    const unsigned Sxi = sxp[0][row] + sxp[1][row] + sxp[2][row] + sxp[3][row];
    const unsigned Swi = swsum[pp];
    const int b = blockIdx.y * 64 + row;
    const int p = c0 + pp;
    const float fSx = (float)Sxi;
    const float fSw = (float)Swi;
    const float I = 0.5f * (fSx + fSw - (float)D);
    // All terms in int units (255x real); eps scales by 255.
    const float denom = I + alpha * (fSx - I) + beta * (fSw - I) + 255.0f * 1e-8f;
    out[b * PDIM + p] = I / denom + bias[p];
  }
}

extern "C" void kernel_launch(void* const* d_in, const int* in_sizes, int n_in,
                              void* d_out, int out_size, void* d_ws, size_t ws_size,
                              hipStream_t stream) {
  const float* x = (const float*)d_in[0];
  const float* w = (const float*)d_in[1];
  const float* bias = (const float*)d_in[2];
  const float* alpha = (const float*)d_in[3];
  const float* beta = (const float*)d_in[4];
  float* out = (float*)d_out;

  // Workspace: exactly 1 MB (xq 512 KB + wq 512 KB). No other scratch.
  unsigned char* ws = (unsigned char*)d_ws;
  unsigned* xq = (unsigned*)ws;
  unsigned* wq = (unsigned*)(ws + 512 * 1024);

  quant_kernel<<<dim3(1024), dim3(256), 0, stream>>>(x, w, xq, wq);
  tversky_pair<<<dim3(PDIM / 8, BDIM / 64), dim3(256), 0, stream>>>(
      xq, wq, bias, alpha, beta, out);
}

// Round 3
// 72.956 us; speedup vs baseline: 1.0496x; 1.0496x over previous
//
#include <hip/hip_runtime.h>

#define FDIM 1024
#define FD4 256   // dwords per quantized row
#define BDIM 512
#define PDIM 512

__device__ __forceinline__ unsigned sad8(unsigned a, unsigned b, unsigned c) {
  return __builtin_amdgcn_sad_u8(a, b, c);  // sum_{4 bytes} |a_i - b_i| + c
}

__device__ __forceinline__ unsigned quant4(float4 v) {
  float s0 = 1.f / (1.f + __expf(-v.x));
  float s1 = 1.f / (1.f + __expf(-v.y));
  float s2 = 1.f / (1.f + __expf(-v.z));
  float s3 = 1.f / (1.f + __expf(-v.w));
  unsigned q0 = (unsigned)(s0 * 255.f + 0.5f);
  unsigned q1 = (unsigned)(s1 * 255.f + 0.5f);
  unsigned q2 = (unsigned)(s2 * 255.f + 0.5f);
  unsigned q3 = (unsigned)(s3 * 255.f + 0.5f);
  return q0 | (q1 << 8) | (q2 << 16) | (q3 << 24);
}

// Blocks 0..511: quantize w row -> row-major wq.
// Blocks 512..543: quantize a 64-row x 64-dword x tile -> TRANSPOSED xqT[d][b]
// via padded LDS tile (coalesced global reads AND writes, conflict-free LDS).
__global__ __launch_bounds__(256) void quant_kernel(
    const float* __restrict__ x, const float* __restrict__ w,
    unsigned* __restrict__ xqT, unsigned* __restrict__ wq) {
  __shared__ unsigned lt[64 * 65];
  const int tid = threadIdx.x;
  if (blockIdx.x < PDIM) {
    const int row = blockIdx.x;
    float4 v = ((const float4*)(w + (size_t)row * FDIM))[tid];
    wq[row * FD4 + tid] = quant4(v);
  } else {
    const int t = blockIdx.x - PDIM;  // 0..31
    const int r0 = (t >> 2) * 64;     // b-row base
    const int d0 = (t & 3) * 64;      // dword-col base
#pragma unroll
    for (int j = 0; j < 16; ++j) {
      const int flat = tid + 256 * j;       // 0..4095
      const int row = flat >> 6;            // 0..63
      const int c4 = flat & 63;             // 0..63
      float4 v = ((const float4*)x)[(r0 + row) * FD4 + d0 + c4];
      lt[row * 65 + c4] = quant4(v);
    }
    __syncthreads();
#pragma unroll
    for (int j = 0; j < 16; ++j) {
      const int flat = tid + 256 * j;
      const int dc = flat >> 6;
      const int b = flat & 63;
      xqT[(d0 + dc) * BDIM + r0 + b] = lt[b * 65 + dc];
    }
  }
}

// Block: 64 b-rows (lane) x 8 p-cols; 4 waves split F (64 dwords each).
// x slice: coalesced loads from transposed xqT into 64 VGPRs.
// w slice: wave-uniform addresses (via readfirstlane) -> scalar-load eligible.
__global__ __launch_bounds__(256) void tversky_pair(
    const unsigned* __restrict__ xqT, const unsigned* __restrict__ wq,
    const float* __restrict__ bias, const float* __restrict__ alphap,
    const float* __restrict__ betap, float* __restrict__ out) {
  const int tid = threadIdx.x;
  const int lane = tid & 63;
  const int wv = __builtin_amdgcn_readfirstlane(tid >> 6);  // F-slice, uniform
  const int r = blockIdx.y * 64 + lane;  // b row
  const int c0 = blockIdx.x * 8;         // p col base

  __shared__ unsigned part[4][8][64];
  __shared__ unsigned sxp[4][64];
  __shared__ unsigned swsum[8];
  if (tid < 8) swsum[tid] = 0;
  __syncthreads();

  // x slice: 64 coalesced dword loads (lane-contiguous in xqT).
  unsigned xv[64];
#pragma unroll
  for (int k = 0; k < 64; ++k) xv[k] = xqT[(wv * 64 + k) * BDIM + r];

  // Sx slice sum (sad vs 0 = byte sum).
  unsigned sx = 0;
#pragma unroll
  for (int k = 0; k < 64; ++k) sx = sad8(xv[k], 0u, sx);
  sxp[wv][lane] = sx;

  // Sw for this block's 8 w rows.
  {
    const int wrow = tid >> 5;
    const int seg = tid & 31;
    const unsigned* wp = wq + (c0 + wrow) * FD4 + seg * 8;
    unsigned s = 0;
#pragma unroll
    for (int j = 0; j < 8; ++j) s = sad8(wp[j], 0u, s);
    atomicAdd(&swsum[wrow], s);
  }

  // Main loop: 8 cols x 64 sads, 4 chains; w via uniform (scalar) loads.
  for (int pp = 0; pp < 8; ++pp) {
    const unsigned* wp = wq + (c0 + pp) * FD4 + wv * 64;
    unsigned a0 = 0, a1 = 0, a2 = 0, a3 = 0;
#pragma unroll
    for (int j = 0; j < 16; ++j) {
      a0 = sad8(xv[4 * j + 0], wp[4 * j + 0], a0);
      a1 = sad8(xv[4 * j + 1], wp[4 * j + 1], a1);
      a2 = sad8(xv[4 * j + 2], wp[4 * j + 2], a2);
      a3 = sad8(xv[4 * j + 3], wp[4 * j + 3], a3);
    }
    part[wv][pp][lane] = a0 + a1 + a2 + a3;
  }
  __syncthreads();

  const float alpha = alphap[0];
  const float beta = betap[0];
#pragma unroll
  for (int id = tid; id < 512; id += 256) {
    const int row = id >> 3;
    const int pp = id & 7;
    const unsigned D = part[0][pp][row] + part[1][pp][row] +
                       part[2][pp][row] + part[3][pp][row];
    const unsigned Sxi = sxp[0][row] + sxp[1][row] + sxp[2][row] + sxp[3][row];
    const unsigned Swi = swsum[pp];
    const int b = blockIdx.y * 64 + row;
    const int p = c0 + pp;
    const float fSx = (float)Sxi;
    const float fSw = (float)Swi;
    const float I = 0.5f * (fSx + fSw - (float)D);
    // All terms in int units (255x real); eps scales by 255.
    const float denom = I + alpha * (fSx - I) + beta * (fSw - I) + 255.0f * 1e-8f;
    out[b * PDIM + p] = I / denom + bias[p];
  }
}

extern "C" void kernel_launch(void* const* d_in, const int* in_sizes, int n_in,
                              void* d_out, int out_size, void* d_ws, size_t ws_size,
                              hipStream_t stream) {
  const float* x = (const float*)d_in[0];
  const float* w = (const float*)d_in[1];
  const float* bias = (const float*)d_in[2];
  const float* alpha = (const float*)d_in[3];
  const float* beta = (const float*)d_in[4];
  float* out = (float*)d_out;

  unsigned char* ws = (unsigned char*)d_ws;
  unsigned* xqT = (unsigned*)ws;                 // 512 KB, transposed [256][512]
  unsigned* wq = (unsigned*)(ws + 512 * 1024);   // 512 KB, row-major [512][256]

  quant_kernel<<<dim3(PDIM + 32), dim3(256), 0, stream>>>(x, w, xqT, wq);
  tversky_pair<<<dim3(PDIM / 8, BDIM / 64), dim3(256), 0, stream>>>(
      xqT, wq, bias, alpha, beta, out);
}

// Round 4
// 70.200 us; speedup vs baseline: 1.0908x; 1.0393x over previous
//
#include <hip/hip_runtime.h>

#define FDIM 1024
#define FD4 256   // dwords per quantized row
#define BDIM 512
#define PDIM 512

__device__ __forceinline__ unsigned sad8(unsigned a, unsigned b, unsigned c) {
  return __builtin_amdgcn_sad_u8(a, b, c);  // sum_{4 bytes} |a_i - b_i| + c
}

__device__ __forceinline__ unsigned quant4(float4 v) {
  float s0 = 1.f / (1.f + __expf(-v.x));
  float s1 = 1.f / (1.f + __expf(-v.y));
  float s2 = 1.f / (1.f + __expf(-v.z));
  float s3 = 1.f / (1.f + __expf(-v.w));
  unsigned q0 = (unsigned)(s0 * 255.f + 0.5f);
  unsigned q1 = (unsigned)(s1 * 255.f + 0.5f);
  unsigned q2 = (unsigned)(s2 * 255.f + 0.5f);
  unsigned q3 = (unsigned)(s3 * 255.f + 0.5f);
  return q0 | (q1 << 8) | (q2 << 16) | (q3 << 24);
}

// Blocks 0..511: quantize one w row -> row-major wq (1 float4/thread).
// Blocks 512..575: transpose-quantize a 64-row x 32-dword x tile -> xqT[d][b]
// via padded LDS (stride 33, conflict-free both directions), 8 light iters.
__global__ __launch_bounds__(256) void quant_kernel(
    const float* __restrict__ x, const float* __restrict__ w,
    unsigned* __restrict__ xqT, unsigned* __restrict__ wq) {
  __shared__ unsigned lt[64 * 33];
  const int tid = threadIdx.x;
  if (blockIdx.x < PDIM) {
    const int row = blockIdx.x;
    float4 v = ((const float4*)(w + (size_t)row * FDIM))[tid];
    wq[row * FD4 + tid] = quant4(v);
  } else {
    const int t = blockIdx.x - PDIM;  // 0..63
    const int r0 = (t & 7) * 64;      // b-row base (8 row-tiles)
    const int d0 = (t >> 3) * 32;     // dword-col base (8 col-tiles)
#pragma unroll
    for (int k = 0; k < 8; ++k) {
      const int flat = tid + 256 * k;  // 0..2047
      const int row = flat >> 5;       // 0..63
      const int c = flat & 31;         // 0..31
      float4 v = ((const float4*)x)[(r0 + row) * FD4 + d0 + c];
      lt[row * 33 + c] = quant4(v);
    }
    __syncthreads();
#pragma unroll
    for (int k = 0; k < 8; ++k) {
      const int flat = tid + 256 * k;
      const int dc = flat >> 6;        // 0..31
      const int b = flat & 63;         // 0..63
      xqT[(d0 + dc) * BDIM + r0 + b] = lt[b * 33 + dc];
    }
  }
}

// Block: 64 b-rows (lane) x 8 p-cols; 4 waves split F (64 dwords each).
// x slice: coalesced loads from transposed xqT into 64 VGPRs.
// w slice: wave-uniform addresses (readfirstlane) -> scalar s_load eligible.
__global__ __launch_bounds__(256) void tversky_pair(
    const unsigned* __restrict__ xqT, const unsigned* __restrict__ wq,
    const float* __restrict__ bias, const float* __restrict__ alphap,
    const float* __restrict__ betap, float* __restrict__ out) {
  const int tid = threadIdx.x;
  const int lane = tid & 63;
  const int wv = __builtin_amdgcn_readfirstlane(tid >> 6);  // F-slice, uniform
  const int r = blockIdx.y * 64 + lane;  // b row
  const int c0 = blockIdx.x * 8;         // p col base

  __shared__ unsigned part[4][8][64];
  __shared__ unsigned sxp[4][64];
  __shared__ unsigned swsum[8];
  if (tid < 8) swsum[tid] = 0;
  __syncthreads();

  // x slice: 64 coalesced dword loads (lane-contiguous in xqT).
  unsigned xv[64];
#pragma unroll
  for (int k = 0; k < 64; ++k) xv[k] = xqT[(wv * 64 + k) * BDIM + r];

  // Sx slice sum (sad vs 0 = byte sum).
  unsigned sx = 0;
#pragma unroll
  for (int k = 0; k < 64; ++k) sx = sad8(xv[k], 0u, sx);
  sxp[wv][lane] = sx;

  // Sw for this block's 8 w rows.
  {
    const int wrow = tid >> 5;
    const int seg = tid & 31;
    const unsigned* wp = wq + (c0 + wrow) * FD4 + seg * 8;
    unsigned s = 0;
#pragma unroll
    for (int j = 0; j < 8; ++j) s = sad8(wp[j], 0u, s);
    atomicAdd(&swsum[wrow], s);
  }

  // Main loop: 8 cols x 64 sads, 4 chains; w via uniform (scalar) loads.
  for (int pp = 0; pp < 8; ++pp) {
    const unsigned* wp = wq + (c0 + pp) * FD4 + wv * 64;
    unsigned a0 = 0, a1 = 0, a2 = 0, a3 = 0;
#pragma unroll
    for (int j = 0; j < 16; ++j) {
      a0 = sad8(xv[4 * j + 0], wp[4 * j + 0], a0);
      a1 = sad8(xv[4 * j + 1], wp[4 * j + 1], a1);
      a2 = sad8(xv[4 * j + 2], wp[4 * j + 2], a2);
      a3 = sad8(xv[4 * j + 3], wp[4 * j + 3], a3);
    }
    part[wv][pp][lane] = a0 + a1 + a2 + a3;
  }
  __syncthreads();

  const float alpha = alphap[0];
  const float beta = betap[0];
#pragma unroll
  for (int id = tid; id < 512; id += 256) {
    const int row = id >> 3;
    const int pp = id & 7;
    const unsigned D = part[0][pp][row] + part[1][pp][row] +
                       part[2][pp][row] + part[3][pp][row];
    const unsigned Sxi = sxp[0][row] + sxp[1][row] + sxp[2][row] + sxp[3][row];
    const unsigned Swi = swsum[pp];
    const int b = blockIdx.y * 64 + row;
    const int p = c0 + pp;
    const float fSx = (float)Sxi;
    const float fSw = (float)Swi;
    const float I = 0.5f * (fSx + fSw - (float)D);
    // All terms in int units (255x real); eps scales by 255.
    const float denom = I + alpha * (fSx - I) + beta * (fSw - I) + 255.0f * 1e-8f;
    out[b * PDIM + p] = I / denom + bias[p];
  }
}

extern "C" void kernel_launch(void* const* d_in, const int* in_sizes, int n_in,
                              void* d_out, int out_size, void* d_ws, size_t ws_size,
                              hipStream_t stream) {
  const float* x = (const float*)d_in[0];
  const float* w = (const float*)d_in[1];
  const float* bias = (const float*)d_in[2];
  const float* alpha = (const float*)d_in[3];
  const float* beta = (const float*)d_in[4];
  float* out = (float*)d_out;

  unsigned char* ws = (unsigned char*)d_ws;
  unsigned* xqT = (unsigned*)ws;                 // 512 KB, transposed [256][512]
  unsigned* wq = (unsigned*)(ws + 512 * 1024);   // 512 KB, row-major [512][256]

  quant_kernel<<<dim3(PDIM + 64), dim3(256), 0, stream>>>(x, w, xqT, wq);
  tversky_pair<<<dim3(PDIM / 8, BDIM / 64), dim3(256), 0, stream>>>(
      xqT, wq, bias, alpha, beta, out);
}